// Round 3
// baseline (223.381 us; speedup 1.0000x reference)
//
#include <hip/hip_runtime.h>
#include <math.h>

// Problem constants (fixed by setup_inputs)
#define BATCH 8
#define CH    256
#define H     128
#define W     128
#define PLANE (H * W)            // 16384
#define NPIX  (BATCH * PLANE)    // 131072
#define NSHIFT 12                // symmetric half of the 24 shifts
#define NMAPS  13                // 12 shifted dots + normsq
#define NCHUNK 4                 // channel chunks
#define CPC    (CH / NCHUNK)     // 64 channels per chunk
#define CSTRIDE (NMAPS * NPIX)   // floats per chunk slice (1703936)

// 12 "positive" shifts: dy>0 or (dy==0 && dx>0). Negatives recovered by symmetry.
static __device__ __constant__ int S_DY[NSHIFT] = {0,0,1,1,1,1,1,2,2,2,2,2};
static __device__ __constant__ int S_DX[NSHIFT] = {1,2,-2,-1,0,1,2,-2,-1,0,1,2};

// R3 retile: 16-row tiles, 1024-thread blocks -> 256 corr blocks = 1/CU exactly.
#define TROWS  16
#define SROWS  (TROWS + 2)                       // 18 staged rows (bottom halo only)
#define NTILE  (H / TROWS)                       // 8
#define NCORRB (BATCH * NTILE * NCHUNK)          // 256 corr blocks

__device__ __forceinline__ void fma4(float& acc, const float4& a, const float4& b) {
    acc = fmaf(a.x, b.x, acc);
    acc = fmaf(a.y, b.y, acc);
    acc = fmaf(a.z, b.z, acc);
    acc = fmaf(a.w, b.w, acc);
}

// ---------------------------------------------------------------------------
// Kernel P: tiny init (comb written exactly once per address in k_corr).
// ---------------------------------------------------------------------------
__global__ __launch_bounds__(64) void k_prep(int* __restrict__ cnt,
                                             int* __restrict__ inc,
                                             float* __restrict__ tot) {
    int t = threadIdx.x;
    if (t < 8) { cnt[t] = 0; inc[t] = 0; tot[t] = 0.0f; }
}

// ---------------------------------------------------------------------------
// Kernel C: pure correlation (stats moved to k_loss — R3: the 256 stats
// blocks shared k_corr's static LDS footprint and serialized as a tail
// behind the corr wave).
// Grid decode: chunk(4) | tile(8) | b(8) = 256 blocks, 1024 thr.
// Each thread computes 2 adjacent output rows (block covers 16 rows,
// stages 18 rows x 4 channels as float4-per-pixel in LDS; halo
// amplification 1.125x vs 1.25x at TROWS=8).
// Double-buffered LDS (one barrier per channel-quad) + depth-2 register
// prefetch: quad k+2's global loads issue during quad k's compute.
// __launch_bounds__(1024,4): 16 waves = 1 block/CU, 128-VGPR budget.
// ---------------------------------------------------------------------------
__global__ __launch_bounds__(1024, 4) void k_corr(const float* __restrict__ er,
                                                  float* __restrict__ comb) {
    __shared__ float4 lds[2][SROWS][132];   // 2 buffers, 18 rows, x padded 2/side
    int t = threadIdx.x;

    int blk = blockIdx.x;
    int chunk = blk & 3;
    int tile  = (blk >> 2) & 7;
    int b     = blk >> 5;
    int y0 = tile * TROWS;           // block covers output rows y0..y0+15
    int c0 = chunk * CPC;
    int r = t >> 7;                  // thread handles output rows y0+2r, y0+2r+1
    int x = t & 127;

    // zero the x-pad slots of BOTH buffers once (first barrier makes visible)
    if (t < 2 * SROWS * 4) {         // 144
        int bi = t / (SROWS * 4), rem = t % (SROWS * 4);
        int row = rem >> 2, col = rem & 3;
        int xs = (col < 2) ? col : (col + 128);   // 0,1,130,131
        lds[bi][row][xs] = make_float4(0.f, 0.f, 0.f, 0.f);
    }

    float accA[13], accB[13];
#pragma unroll
    for (int i = 0; i < 13; i++) { accA[i] = 0.0f; accB[i] = 0.0f; }

    const float* base = er + (size_t)b * CH * PLANE;

    // prefetch registers: up to 3 stage slots x 4 channels (slot 2: t<256 only;
    // staged px = 18*128 = 2304 = 2.25 * 1024)
    float pf[3][4];
    auto load_quad = [&](int c) {
#pragma unroll
        for (int k = 0; k < 3; ++k) {
            if (k < 2 || t < 256) {
                int s = t + k * 1024;        // 0..2303
                int row = s >> 7;            // 0..17
                int xs = s & 127;
                int y = y0 + row;
                if (y < H) {
                    const float* p0 = base + (size_t)c * PLANE + y * W + xs;
                    pf[k][0] = p0[0];
                    pf[k][1] = p0[PLANE];
                    pf[k][2] = p0[2 * PLANE];
                    pf[k][3] = p0[3 * PLANE];
                } else {
                    pf[k][0] = 0.f; pf[k][1] = 0.f; pf[k][2] = 0.f; pf[k][3] = 0.f;
                }
            }
        }
    };
    auto commit_quad = [&](int bi) {
#pragma unroll
        for (int k = 0; k < 3; ++k) {
            if (k < 2 || t < 256) {
                int s = t + k * 1024;
                int row = s >> 7;
                int xs = s & 127;
                lds[bi][row][xs + 2] = make_float4(pf[k][0], pf[k][1], pf[k][2], pf[k][3]);
            }
        }
    };

    const int iters = CPC / 4;       // 16
    // prologue: quad 0 -> buf0; quad 1 in flight
    load_quad(c0);
    commit_quad(0);
    load_quad(c0 + 4);

    auto iter = [&](int it, int cur) {
        __syncthreads();   // buf[cur] writes visible; buf[cur^1] reads (prev iter) done
        if (it + 1 < iters) commit_quad(cur ^ 1);          // vmcnt wait lands here
        if (it + 2 < iters) load_quad(c0 + 4 * (it + 2));  // overlaps compute below

        const float4* lp = &lds[cur][2 * r][x + 2];
        float4 cA = lp[0];               // (rel row 0, dx 0)
        float4 cB = lp[132];             // (rel row 1, dx 0)
        // rel row 0: dx {0,1,2} -> accA[0..2]
        {
            float4 v1 = lp[1], v2 = lp[2];
            fma4(accA[0], cA, cA);
            fma4(accA[1], cA, v1);
            fma4(accA[2], cA, v2);
        }
        // rel row 1: dx {-2..2} -> accA[3..7]; accB[0..2] (dx 0,1,2)
        {
            float4 m2 = lp[130], m1 = lp[131], p1 = lp[133], p2 = lp[134];
            fma4(accA[3], cA, m2);
            fma4(accA[4], cA, m1);
            fma4(accA[5], cA, cB);
            fma4(accA[6], cA, p1);
            fma4(accA[7], cA, p2);
            fma4(accB[0], cB, cB);
            fma4(accB[1], cB, p1);
            fma4(accB[2], cB, p2);
        }
        // rel row 2: dx {-2..2} -> accA[8..12]; accB[3..7]
        {
            float4 m2 = lp[262], m1 = lp[263], v0 = lp[264], p1 = lp[265], p2 = lp[266];
            fma4(accA[8],  cA, m2);
            fma4(accA[9],  cA, m1);
            fma4(accA[10], cA, v0);
            fma4(accA[11], cA, p1);
            fma4(accA[12], cA, p2);
            fma4(accB[3], cB, m2);
            fma4(accB[4], cB, m1);
            fma4(accB[5], cB, v0);
            fma4(accB[6], cB, p1);
            fma4(accB[7], cB, p2);
        }
        // rel row 3: dx {-2..2} -> accB[8..12]
        {
            float4 m2 = lp[394], m1 = lp[395], v0 = lp[396], p1 = lp[397], p2 = lp[398];
            fma4(accB[8],  cB, m2);
            fma4(accB[9],  cB, m1);
            fma4(accB[10], cB, v0);
            fma4(accB[11], cB, p1);
            fma4(accB[12], cB, p2);
        }
    };

    for (int it = 0; it < iters; it += 2) {
        iter(it, 0);
        iter(it + 1, 1);
    }

    // plain coalesced stores into this chunk's private slice
    float* cb = comb + (size_t)chunk * CSTRIDE;
    int pixA = b * PLANE + (y0 + 2 * r) * W + x;
    int pixB = pixA + W;
#pragma unroll
    for (int m = 0; m < NSHIFT; ++m) {
        cb[m * NPIX + pixA] = accA[m + 1];
        cb[m * NPIX + pixB] = accB[m + 1];
    }
    cb[NSHIFT * NPIX + pixA] = accA[0];
    cb[NSHIFT * NPIX + pixB] = accB[0];
}

// ---------------------------------------------------------------------------
// Kernel R: per-pixel reciprocal norm = 1/max(sqrt(sum_c normsq), 1e-8).
// ---------------------------------------------------------------------------
__global__ __launch_bounds__(256) void k_rn(const float* __restrict__ comb,
                                            float* __restrict__ rn) {
    int idx = blockIdx.x * 256 + threadIdx.x;
    const float* ns = comb + NSHIFT * NPIX;
    float s = (ns[idx] + ns[idx + CSTRIDE]) + (ns[idx + 2 * CSTRIDE] + ns[idx + 3 * CSTRIDE]);
    rn[idx] = fminf(rsqrtf(s), 1e8f);   // s==0 -> inf -> clamp = 1/1e-8
}

// ---------------------------------------------------------------------------
// Kernel L: per-valid-pixel loss assembly + per-image stats, all fused.
// Accumulates RAW per-image {sum, cnt, any} — normalization deferred to
// k_fin (removes the cnt/inc dependency from every block's prologue).
// ---------------------------------------------------------------------------
__device__ __forceinline__ float sum4c(const float* __restrict__ p) {
    return (p[0] + p[CSTRIDE]) + (p[2 * CSTRIDE] + p[3 * CSTRIDE]);
}

__global__ __launch_bounds__(256) void k_loss(const float* __restrict__ comb,
                                              const float* __restrict__ rn,
                                              const int* __restrict__ seg,
                                              const int* __restrict__ gtb,
                                              int* __restrict__ cnt,
                                              int* __restrict__ inc,
                                              float* __restrict__ tot) {
    const float* dots = comb;                  // + i*NPIX per map (chunk 0 slice)
    int idx = blockIdx.x * 256 + threadIdx.x;
    int b = idx >> 14;                         // uniform per block (256 | PLANE)
    int rem = idx & (PLANE - 1);
    int y = rem >> 7;
    int x = rem & 127;

    float val = 0.0f;
    int my_cnt = 0, my_any = 0;
    {
        int sp = seg[idx];
        int gp = gtb[idx];
        int s0 = (sp == 255) ? 0 : sp;
        int g0 = (gp == 255) ? 0 : gp;
        if (s0 > 0 && g0 > 0) {
            my_any = 1;
            if (y >= 2 && y < H - 2 && x >= 2 && x < W - 2) {
                my_cnt = 1;
                float npr = rn[idx];
                float sum = 0.0f;
#pragma unroll
                for (int i = 0; i < NSHIFT; ++i) {
                    int off = S_DY[i] * W + S_DX[i];
                    // + shift: cos(p, p+d)
                    {
                        float d  = sum4c(dots + i * NPIX + idx);
                        float cosv = d * (npr * rn[idx + off]);
                        int sq = seg[idx + off];
                        float lab = (sp == sq && sp < 2) ? 1.0f : 0.0f;
                        float tt = cosv - lab;
                        sum = fmaf(tt, tt, sum);
                    }
                    // - shift: cos(p, p-d) = dot_d(p-d)/(norm(p)norm(p-d))
                    {
                        float d  = sum4c(dots + i * NPIX + idx - off);
                        float cosv = d * (npr * rn[idx - off]);
                        int sq = seg[idx - off];
                        float lab = (sp == sq && sp < 2) ? 1.0f : 0.0f;
                        float tt = cosv - lab;
                        sum = fmaf(tt, tt, sum);
                    }
                }
                val = sum;
            }
        }
    }

    // block reduction: wave shuffle then LDS across 4 waves
    for (int o = 32; o > 0; o >>= 1) {
        val    += __shfl_down(val, o, 64);
        my_cnt += __shfl_down(my_cnt, o, 64);
        my_any |= __shfl_down(my_any, o, 64);
    }
    __shared__ float wsum[4];
    __shared__ int wc[4], wa[4];
    int lane = threadIdx.x & 63;
    int wid  = threadIdx.x >> 6;
    if (lane == 0) { wsum[wid] = val; wc[wid] = my_cnt; wa[wid] = my_any; }
    __syncthreads();
    if (threadIdx.x == 0) {
        float s = wsum[0] + wsum[1] + wsum[2] + wsum[3];
        int c = wc[0] + wc[1] + wc[2] + wc[3];
        int a = wa[0] | wa[1] | wa[2] | wa[3];
        if (s != 0.0f) atomicAdd(&tot[b], s);
        if (c) atomicAdd(&cnt[b], c);
        if (a) atomicOr(&inc[b], 1);
    }
}

// ---------------------------------------------------------------------------
// Kernel F: final normalization.
// out = ( sum_b inc_b ? tot_b / (24 * max(cnt_b,1)) : 0 ) / max(sum inc_b, 1)
// ---------------------------------------------------------------------------
__global__ __launch_bounds__(64) void k_fin(const int* __restrict__ cnt,
                                            const int* __restrict__ inc,
                                            const float* __restrict__ tot,
                                            float* __restrict__ out) {
    if (threadIdx.x == 0) {
        int sn = 0;
        float s = 0.0f;
#pragma unroll
        for (int b = 0; b < BATCH; ++b) {
            int ib = inc[b];
            sn += (ib != 0);
            int cb = cnt[b]; if (cb < 1) cb = 1;
            if (ib) s += tot[b] / (24.0f * (float)cb);
        }
        if (sn < 1) sn = 1;
        out[0] = s / (float)sn;
    }
}

// ---------------------------------------------------------------------------
extern "C" void kernel_launch(void* const* d_in, const int* in_sizes, int n_in,
                              void* d_out, int out_size, void* d_ws, size_t ws_size,
                              hipStream_t stream) {
    const float* er  = (const float*)d_in[0];
    const int*   seg = (const int*)d_in[1];
    const int*   gtb = (const int*)d_in[2];
    float* out = (float*)d_out;

    float* ws   = (float*)d_ws;
    float* comb = ws;                                  // 4 * 13 * NPIX floats (27.3 MB)
    float* rn   = comb + NCHUNK * CSTRIDE;             // NPIX floats (0.5 MB)
    float* tot  = rn + NPIX;                           // 8 floats
    int*   cnt  = (int*)(tot + 8);                     // 8 ints
    int*   inc  = cnt + 8;                             // 8 ints

    hipLaunchKernelGGL(k_prep, dim3(1), dim3(64), 0, stream, cnt, inc, tot);
    hipLaunchKernelGGL(k_corr, dim3(NCORRB), dim3(1024), 0, stream, er, comb);
    hipLaunchKernelGGL(k_rn, dim3(NPIX / 256), dim3(256), 0, stream, comb, rn);
    hipLaunchKernelGGL(k_loss, dim3(NPIX / 256), dim3(256), 0, stream,
                       comb, rn, seg, gtb, cnt, inc, tot);
    hipLaunchKernelGGL(k_fin, dim3(1), dim3(64), 0, stream, cnt, inc, tot, out);
}